// Round 3
// baseline (626.974 us; speedup 1.0000x reference)
//
#include <hip/hip_runtime.h>
#include <cstdint>
#include <cstddef>

#define IN_F 512
#define C1 64      // H1*F1
#define NH 8
#define FD 8
#define C2 40
#define NEG 0.2f

typedef __attribute__((ext_vector_type(8))) short bf16x8;
typedef __attribute__((ext_vector_type(4))) float f32x4;

__device__ inline unsigned short f32_to_bf16_rne(float f) {
    unsigned int u = __float_as_uint(f);
    unsigned int r = (u + 0x7FFFu + ((u >> 16) & 1u)) >> 16;
    return (unsigned short)r;
}
__device__ inline float bf16_to_f32(unsigned short s) {
    return __uint_as_float(((unsigned int)s) << 16);
}

// ---------------- CSR build ----------------
// fire-and-forget histogram (no returned value, no pos array)
__global__ __launch_bounds__(256) void hist_k(const int* __restrict__ dst, int* __restrict__ deg, int E) {
    int e = blockIdx.x * 256 + threadIdx.x;
    if (e < E) atomicAdd(&deg[dst[e]], 1);
}

__global__ __launch_bounds__(1024) void scan_local_k(const int* __restrict__ deg, int* __restrict__ rowp,
                                                     int* __restrict__ bsums, int n) {
    __shared__ int tmp[1024];
    int tx = threadIdx.x;
    int i = blockIdx.x * 1024 + tx;
    int v = (i < n) ? deg[i] : 0;
    tmp[tx] = v;
    __syncthreads();
    for (int d = 1; d < 1024; d <<= 1) {
        int t = (tx >= d) ? tmp[tx - d] : 0;
        __syncthreads();
        tmp[tx] += t;
        __syncthreads();
    }
    if (i < n) rowp[i] = tmp[tx] - v;   // exclusive within block
    if (tx == 1023) bsums[blockIdx.x] = tmp[tx];   // raw block total
}

// fused: each block reduces bsums[0..blockIdx.x) itself (nb <= 128); also emits cursor copy
__global__ __launch_bounds__(1024) void scan_add_k(int* rowp, int* __restrict__ cur,
                                                   const int* __restrict__ bsums, int n, int nb) {
    __shared__ int red[128];
    int tx = threadIdx.x;
    if (tx < 128) red[tx] = (tx < blockIdx.x && tx < nb) ? bsums[tx] : 0;
    __syncthreads();
    if (tx < 64) red[tx] += red[tx + 64];
    __syncthreads();
    if (tx < 32) red[tx] += red[tx + 32];
    __syncthreads();
    if (tx < 16) red[tx] += red[tx + 16];
    __syncthreads();
    if (tx < 8) red[tx] += red[tx + 8];
    __syncthreads();
    if (tx < 4) red[tx] += red[tx + 4];
    __syncthreads();
    if (tx < 2) red[tx] += red[tx + 2];
    __syncthreads();
    if (tx == 0) red[0] += red[1];
    __syncthreads();
    int off = red[0];
    int i = blockIdx.x * 1024 + tx;
    if (i < n) {
        int r = rowp[i] + off;
        rowp[i] = r;
        cur[i] = r;
    }
}

__global__ __launch_bounds__(256) void scatter_k(const int* __restrict__ src, const int* __restrict__ dst,
                                                 int* __restrict__ cur, int* __restrict__ csr_src, int E) {
    int e = blockIdx.x * 256 + threadIdx.x;
    if (e >= E) return;
    int slot = atomicAdd(&cur[dst[e]], 1);
    csr_src[slot] = src[e];
}

// ---------------- preconvert: W1 -> wt_hi/lo[col][k], W2^T -> w2t_hi/lo[48][64] split-bf16 ----------------
__global__ __launch_bounds__(256) void pre_k(const float* __restrict__ W1, const float* __restrict__ W2,
                                             unsigned short* __restrict__ wt_hi, unsigned short* __restrict__ wt_lo,
                                             unsigned short* __restrict__ w2t_hi, unsigned short* __restrict__ w2t_lo) {
    int id = blockIdx.x * 256 + threadIdx.x;
    if (id < IN_F * C1) {
        int col = id & (C1 - 1);
        int k = id >> 6;
        float w = W1[id];
        unsigned short hb = f32_to_bf16_rne(w);
        unsigned short lb = f32_to_bf16_rne(w - bf16_to_f32(hb));
        wt_hi[(size_t)col * IN_F + k] = hb;
        wt_lo[(size_t)col * IN_F + k] = lb;
    } else {
        int id2 = id - IN_F * C1;
        if (id2 < 48 * 64) {
            int c = id2 >> 6, k = id2 & 63;
            float w = (c < C2) ? W2[(size_t)k * C2 + c] : 0.f;
            unsigned short hb = f32_to_bf16_rne(w);
            unsigned short lb = f32_to_bf16_rne(w - bf16_to_f32(hb));
            w2t_hi[c * 64 + k] = hb;
            w2t_lo[c * 64 + k] = lb;
        }
    }
}

// ---------------- GEMM1 via split-bf16 MFMA; epilogue emits bf16 h rows + fused attn1 ----------------
__global__ __launch_bounds__(256) void gemm1_mfma_k(const float* __restrict__ x,
                                                    const unsigned short* __restrict__ wt_hi,
                                                    const unsigned short* __restrict__ wt_lo,
                                                    const float* __restrict__ al, const float* __restrict__ ar,
                                                    unsigned short* __restrict__ hb_out,
                                                    float* __restrict__ el, float* __restrict__ er, int N) {
    __shared__ alignas(16) unsigned short wlds[2][8192];   // 32 KB
    const int tid = threadIdx.x;
    const int wave = tid >> 6, lane = tid & 63;
    const int m = lane & 15, q = lane >> 4;
    const int row = blockIdx.x * 64 + wave * 16 + m;
    const int row_c = row < N ? row : N - 1;
    const float* xp = x + (size_t)row_c * IN_F + q * 8;

    f32x4 acc[4];
#pragma unroll
    for (int ct = 0; ct < 4; ct++) acc[ct] = (f32x4){0.f, 0.f, 0.f, 0.f};
    float4 xr[2][4];

#define WLOAD(c, buf)                                                                              \
    {                                                                                              \
        _Pragma("unroll") for (int j_ = 0; j_ < 4; j_++) {                                         \
            int slot_ = j_ * 256 + wave * 64 + lane;                                               \
            const unsigned short* gbase_ = (slot_ < 512) ? wt_hi : wt_lo;                          \
            int s_ = slot_ & 511;                                                                  \
            int col_ = s_ & 63, kq_ = s_ >> 6;                                                     \
            const unsigned short* g_ = gbase_ + (size_t)col_ * IN_F + (c) * 64 + kq_ * 8;          \
            unsigned short* l_ = &wlds[buf][0] + (size_t)(j_ * 256 + wave * 64) * 8;               \
            __builtin_amdgcn_global_load_lds((const __attribute__((address_space(1))) unsigned int*)g_, \
                                             (__attribute__((address_space(3))) unsigned int*)l_,  \
                                             16, 0, 0);                                            \
        }                                                                                          \
    }
#define XLOAD(c, r)                                  \
    {                                                \
        const float* xsrc_ = xp + (c) * 64;          \
        (r)[0] = *(const float4*)(xsrc_);            \
        (r)[1] = *(const float4*)(xsrc_ + 4);        \
        (r)[2] = *(const float4*)(xsrc_ + 32);       \
        (r)[3] = *(const float4*)(xsrc_ + 36);       \
    }

    WLOAD(0, 0);
    XLOAD(0, xr[0]);

    for (int c = 0; c < 8; c++) {
        int p = c & 1;
        __syncthreads();
        if (c < 7) {
            WLOAD(c + 1, p ^ 1);
            XLOAD(c + 1, xr[p ^ 1]);
        }
#pragma unroll
        for (int ki = 0; ki < 2; ki++) {
            float f[8];
            f[0] = xr[p][ki * 2].x; f[1] = xr[p][ki * 2].y; f[2] = xr[p][ki * 2].z; f[3] = xr[p][ki * 2].w;
            f[4] = xr[p][ki * 2 + 1].x; f[5] = xr[p][ki * 2 + 1].y; f[6] = xr[p][ki * 2 + 1].z; f[7] = xr[p][ki * 2 + 1].w;
            unsigned int u[8], lu[8];
#pragma unroll
            for (int j = 0; j < 8; j++) u[j] = __float_as_uint(f[j]);
            union { uint4 u4; bf16x8 v; } H, L;
            H.u4.x = __builtin_amdgcn_perm(u[1], u[0], 0x07060302u);
            H.u4.y = __builtin_amdgcn_perm(u[3], u[2], 0x07060302u);
            H.u4.z = __builtin_amdgcn_perm(u[5], u[4], 0x07060302u);
            H.u4.w = __builtin_amdgcn_perm(u[7], u[6], 0x07060302u);
#pragma unroll
            for (int j = 0; j < 8; j++)
                lu[j] = __float_as_uint(f[j] - __uint_as_float(u[j] & 0xFFFF0000u));
            L.u4.x = __builtin_amdgcn_perm(lu[1], lu[0], 0x07060302u);
            L.u4.y = __builtin_amdgcn_perm(lu[3], lu[2], 0x07060302u);
            L.u4.z = __builtin_amdgcn_perm(lu[5], lu[4], 0x07060302u);
            L.u4.w = __builtin_amdgcn_perm(lu[7], lu[6], 0x07060302u);
            int kq = ki * 4 + q;
#pragma unroll
            for (int ct = 0; ct < 4; ct++) {
                int slot = kq * 64 + ct * 16 + m;
                bf16x8 bh = *(const bf16x8*)&wlds[p][slot * 8];
                bf16x8 bl = *(const bf16x8*)&wlds[p][4096 + slot * 8];
                acc[ct] = __builtin_amdgcn_mfma_f32_16x16x32_bf16(H.v, bh, acc[ct], 0, 0, 0);
                acc[ct] = __builtin_amdgcn_mfma_f32_16x16x32_bf16(L.v, bh, acc[ct], 0, 0, 0);
                acc[ct] = __builtin_amdgcn_mfma_f32_16x16x32_bf16(H.v, bl, acc[ct], 0, 0, 0);
            }
        }
    }
    int rbase = blockIdx.x * 64 + wave * 16 + q * 4;
#pragma unroll
    for (int r = 0; r < 4; r++) {
        int ro = rbase + r;
        if (ro < N) {
#pragma unroll
            for (int ct = 0; ct < 4; ct++)
                hb_out[(size_t)ro * C1 + ct * 16 + m] = f32_to_bf16_rne(acc[ct][r]);
        }
    }

    // ----- fused attn1: stash fp32 h into LDS, compute el/er for this block's 64 rows -----
    __syncthreads();   // all waves done reading wlds before reuse
    float* hst = (float*)&wlds[0][0];   // [64][69] floats = 17.6 KB
    {
        int rr = wave * 16 + q * 4;
#pragma unroll
        for (int r = 0; r < 4; r++)
#pragma unroll
            for (int ct = 0; ct < 4; ct++)
                hst[(rr + r) * 69 + ct * 16 + m] = acc[ct][r];
    }
    __syncthreads();
    for (int id = tid; id < 512; id += 256) {
        int r = id >> 3, hd = id & 7;
        int nn = blockIdx.x * 64 + r;
        if (nn < N) {
            float e_l = 0.f, e_r = 0.f;
#pragma unroll
            for (int f = 0; f < 8; f++) {
                float v = hst[r * 69 + hd * 8 + f];
                e_l += v * al[hd * 8 + f];
                e_r += v * ar[hd * 8 + f];
            }
            el[(size_t)nn * NH + hd] = e_l;
            er[(size_t)nn * NH + hd] = e_r;
        }
    }
#undef WLOAD
#undef XLOAD
}

// ---------------- fused layer1 aggregate + GEMM2 + attn2 ----------------
// 1024 threads = 16 waves; block owns 64 nodes. Each wave aggregates 4 nodes (quarter-wave
// edge slots, uint2 hb gathers, csr prefetch) into an LDS h1 tile. Waves 0-3 then run the
// split-bf16 MFMA gemm2 on the tile; all threads pack h2b + attn2.
__global__ __launch_bounds__(1024) void l1_gemm2_k(const unsigned short* __restrict__ hb,
                                                   const float* __restrict__ el, const float* __restrict__ er,
                                                   const int* __restrict__ rowp, const int* __restrict__ deg,
                                                   const int* __restrict__ csr_src, const float* __restrict__ b1,
                                                   const unsigned short* __restrict__ w2t_hi,
                                                   const unsigned short* __restrict__ w2t_lo,
                                                   const float* __restrict__ al2, const float* __restrict__ ar2,
                                                   unsigned short* __restrict__ h2b, float* __restrict__ el2,
                                                   float* __restrict__ er2, int N) {
    __shared__ float h1s[64][68];   // 17.4 KB, stride 68 (16B-aligned rows)
    __shared__ float h2s[64][49];   // 12.5 KB
    __shared__ float a2s[2 * C2];
    int t = threadIdx.x;
    int wave = t >> 6, lane = t & 63;
    int n0 = blockIdx.x * 64;
    if (t < C2) a2s[t] = al2[t];
    else if (t < 2 * C2) a2s[t] = ar2[t - C2];

    int q = lane >> 4;
    int f = lane & 15;
    int hd = f >> 1;
    const uint2* hb64 = (const uint2*)hb;   // row = 16 uint2 (64 bf16)

    for (int k = 0; k < 4; k++) {
        int r = wave * 4 + k;       // local row in [0,64)
        int n = n0 + r;
        float o0 = 0.f, o1 = 0.f, o2 = 0.f, o3 = 0.f;
        if (n < N) {
            int start = rowp[n], cnt = deg[n];
            float erd = er[(size_t)n * NH + hd];
            const int* cp = csr_src + start;
            float a0 = 0.f, a1 = 0.f, a2 = 0.f, a3 = 0.f, s = 0.f;
            if (cnt > 0) {
                int lastc = cnt - 1;
                int c0 = cp[(q < cnt) ? q : lastc];
                int c1 = cp[(4 + q < cnt) ? 4 + q : lastc];
                int i = 0;
                while (i + 8 < cnt) {
                    int i8 = i + 8;
                    int c2 = cp[(i8 + q < cnt) ? i8 + q : lastc];
                    int c3 = cp[(i8 + 4 + q < cnt) ? i8 + 4 + q : lastc];
                    float e0 = el[(size_t)c0 * NH + hd] + erd;
                    float e1 = el[(size_t)c1 * NH + hd] + erd;
                    uint2 v0 = hb64[(size_t)c0 * 16 + f];
                    uint2 v1 = hb64[(size_t)c1 * 16 + f];
                    e0 = e0 > 0.f ? e0 : NEG * e0;
                    e1 = e1 > 0.f ? e1 : NEG * e1;
                    float w0 = __expf(e0), w1 = __expf(e1);
                    s += w0 + w1;
                    a0 += w0 * __uint_as_float(v0.x << 16) + w1 * __uint_as_float(v1.x << 16);
                    a1 += w0 * __uint_as_float(v0.x & 0xFFFF0000u) + w1 * __uint_as_float(v1.x & 0xFFFF0000u);
                    a2 += w0 * __uint_as_float(v0.y << 16) + w1 * __uint_as_float(v1.y << 16);
                    a3 += w0 * __uint_as_float(v0.y & 0xFFFF0000u) + w1 * __uint_as_float(v1.y & 0xFFFF0000u);
                    c0 = c2; c1 = c3; i = i8;
                }
                {   // masked tail: edges i+q and i+4+q
                    bool m0 = (i + q) < cnt, m1 = (i + 4 + q) < cnt;
                    float e0 = el[(size_t)c0 * NH + hd] + erd;
                    float e1 = el[(size_t)c1 * NH + hd] + erd;
                    uint2 v0 = hb64[(size_t)c0 * 16 + f];
                    uint2 v1 = hb64[(size_t)c1 * 16 + f];
                    e0 = e0 > 0.f ? e0 : NEG * e0;
                    e1 = e1 > 0.f ? e1 : NEG * e1;
                    float w0 = m0 ? __expf(e0) : 0.f;
                    float w1 = m1 ? __expf(e1) : 0.f;
                    s += w0 + w1;
                    a0 += w0 * __uint_as_float(v0.x << 16) + w1 * __uint_as_float(v1.x << 16);
                    a1 += w0 * __uint_as_float(v0.x & 0xFFFF0000u) + w1 * __uint_as_float(v1.x & 0xFFFF0000u);
                    a2 += w0 * __uint_as_float(v0.y << 16) + w1 * __uint_as_float(v1.y << 16);
                    a3 += w0 * __uint_as_float(v0.y & 0xFFFF0000u) + w1 * __uint_as_float(v1.y & 0xFFFF0000u);
                }
            }
            // cross-quarter reduce
            a0 += __shfl_xor(a0, 16); a0 += __shfl_xor(a0, 32);
            a1 += __shfl_xor(a1, 16); a1 += __shfl_xor(a1, 32);
            a2 += __shfl_xor(a2, 16); a2 += __shfl_xor(a2, 32);
            a3 += __shfl_xor(a3, 16); a3 += __shfl_xor(a3, 32);
            s  += __shfl_xor(s, 16);  s  += __shfl_xor(s, 32);
            float sinv = (s > 0.f) ? 1.f / s : 0.f;
            float4 bv = *(const float4*)(b1 + f * 4);
            o0 = a0 * sinv + bv.x;
            o1 = a1 * sinv + bv.y;
            o2 = a2 * sinv + bv.z;
            o3 = a3 * sinv + bv.w;
            o0 = o0 > 0.f ? o0 : (__expf(o0) - 1.f);
            o1 = o1 > 0.f ? o1 : (__expf(o1) - 1.f);
            o2 = o2 > 0.f ? o2 : (__expf(o2) - 1.f);
            o3 = o3 > 0.f ? o3 : (__expf(o3) - 1.f);
        }
        if (q == 0) *(float4*)&h1s[r][f * 4] = make_float4(o0, o1, o2, o3);
    }
    __syncthreads();

    // ----- gemm2 (waves 0-3): split-bf16 MFMA from the LDS h1 tile -----
    if (wave < 4) {
        int m = lane & 15, qq = lane >> 4;
        f32x4 acc[3];
#pragma unroll
        for (int ct = 0; ct < 3; ct++) acc[ct] = (f32x4){0.f, 0.f, 0.f, 0.f};
#pragma unroll
        for (int ks = 0; ks < 2; ks++) {
            const float* hp = &h1s[wave * 16 + m][qq * 8 + ks * 32];
            float4 r0 = *(const float4*)hp;
            float4 r1 = *(const float4*)(hp + 4);
            float ff[8];
            ff[0] = r0.x; ff[1] = r0.y; ff[2] = r0.z; ff[3] = r0.w;
            ff[4] = r1.x; ff[5] = r1.y; ff[6] = r1.z; ff[7] = r1.w;
            unsigned int u[8], lu[8];
#pragma unroll
            for (int j = 0; j < 8; j++) u[j] = __float_as_uint(ff[j]);
            union { uint4 u4; bf16x8 v; } H, L;
            H.u4.x = __builtin_amdgcn_perm(u[1], u[0], 0x07060302u);
            H.u4.y = __builtin_amdgcn_perm(u[3], u[2], 0x07060302u);
            H.u4.z = __builtin_amdgcn_perm(u[5], u[4], 0x07060302u);
            H.u4.w = __builtin_amdgcn_perm(u[7], u[6], 0x07060302u);
#pragma unroll
            for (int j = 0; j < 8; j++)
                lu[j] = __float_as_uint(ff[j] - __uint_as_float(u[j] & 0xFFFF0000u));
            L.u4.x = __builtin_amdgcn_perm(lu[1], lu[0], 0x07060302u);
            L.u4.y = __builtin_amdgcn_perm(lu[3], lu[2], 0x07060302u);
            L.u4.z = __builtin_amdgcn_perm(lu[5], lu[4], 0x07060302u);
            L.u4.w = __builtin_amdgcn_perm(lu[7], lu[6], 0x07060302u);
            int kb = ks * 32 + qq * 8;
#pragma unroll
            for (int ct = 0; ct < 3; ct++) {
                int col = ct * 16 + m;
                bf16x8 bh = *(const bf16x8*)(w2t_hi + col * 64 + kb);
                bf16x8 bl = *(const bf16x8*)(w2t_lo + col * 64 + kb);
                acc[ct] = __builtin_amdgcn_mfma_f32_16x16x32_bf16(H.v, bh, acc[ct], 0, 0, 0);
                acc[ct] = __builtin_amdgcn_mfma_f32_16x16x32_bf16(L.v, bh, acc[ct], 0, 0, 0);
                acc[ct] = __builtin_amdgcn_mfma_f32_16x16x32_bf16(H.v, bl, acc[ct], 0, 0, 0);
            }
        }
        int rl = wave * 16 + qq * 4;
#pragma unroll
        for (int ct = 0; ct < 3; ct++)
#pragma unroll
            for (int r = 0; r < 4; r++) h2s[rl + r][ct * 16 + m] = acc[ct][r];
    }
    __syncthreads();

    // write unpadded bf16 rows: 20 dwords per row
    unsigned int* h2d = (unsigned int*)h2b;
    for (int o = t; o < 64 * 20; o += 1024) {
        int r = o / 20, cd = o % 20;
        int nn = n0 + r;
        if (nn < N) {
            unsigned int lo16 = f32_to_bf16_rne(h2s[r][cd * 2]);
            unsigned int hi16 = f32_to_bf16_rne(h2s[r][cd * 2 + 1]);
            h2d[(size_t)nn * 20 + cd] = lo16 | (hi16 << 16);
        }
    }
    if (t < 64) {
        int nn = n0 + t;
        if (nn < N) {
            float e_l = 0.f, e_r = 0.f;
#pragma unroll
            for (int c = 0; c < C2; c++) {
                float v = h2s[t][c];
                e_l += v * a2s[c];
                e_r += v * a2s[C2 + c];
            }
            el2[nn] = e_l;
            er2[nn] = e_r;
        }
    }
}

// ---------------- layer2: 8 lanes/node; lanes sub<5 gather (80 B/row), csr prefetch ----------------
__global__ __launch_bounds__(256) void l2_fused_k(const unsigned short* __restrict__ h2b,
                                                  const float* __restrict__ el, const float* __restrict__ er,
                                                  const int* __restrict__ rowp, const int* __restrict__ deg,
                                                  const int* __restrict__ csr_src, const float* __restrict__ b2,
                                                  float* __restrict__ out, int N) {
    int tid = threadIdx.x;
    int n = blockIdx.x * 32 + (tid >> 3);
    int sub = tid & 7;
    if (n >= N) return;
    float vals[8];
    if (sub < 5) {
        int start = rowp[n], cnt = deg[n];
        float erd = er[n];
        float s = 0.f;
        float acc[8];
#pragma unroll
        for (int j = 0; j < 8; j++) acc[j] = 0.f;
        const int* cp = csr_src + start;
        if (cnt > 0) {
            int last = cnt - 1;
            int c0 = cp[0];
            int c1 = cp[1 < cnt ? 1 : last];
            int c2 = cp[2 < cnt ? 2 : last];
            int c3 = cp[3 < cnt ? 3 : last];
            int i = 0;
            while (i + 4 < cnt) {
                int i4 = i + 4;
                int p0 = cp[i4];
                int p1 = cp[(i4 + 1 < cnt) ? i4 + 1 : last];
                int p2 = cp[(i4 + 2 < cnt) ? i4 + 2 : last];
                int p3 = cp[(i4 + 3 < cnt) ? i4 + 3 : last];
                float e0 = el[c0], e1 = el[c1], e2 = el[c2], e3 = el[c3];
                bf16x8 v0 = *(const bf16x8*)(h2b + (size_t)c0 * C2 + sub * 8);
                bf16x8 v1 = *(const bf16x8*)(h2b + (size_t)c1 * C2 + sub * 8);
                bf16x8 v2 = *(const bf16x8*)(h2b + (size_t)c2 * C2 + sub * 8);
                bf16x8 v3 = *(const bf16x8*)(h2b + (size_t)c3 * C2 + sub * 8);
                e0 += erd; e1 += erd; e2 += erd; e3 += erd;
                e0 = e0 > 0.f ? e0 : NEG * e0;
                e1 = e1 > 0.f ? e1 : NEG * e1;
                e2 = e2 > 0.f ? e2 : NEG * e2;
                e3 = e3 > 0.f ? e3 : NEG * e3;
                float w0 = __expf(e0), w1 = __expf(e1), w2 = __expf(e2), w3 = __expf(e3);
                s += (w0 + w1) + (w2 + w3);
#pragma unroll
                for (int j = 0; j < 8; j++) {
                    acc[j] += w0 * bf16_to_f32((unsigned short)v0[j]) + w1 * bf16_to_f32((unsigned short)v1[j]) +
                              w2 * bf16_to_f32((unsigned short)v2[j]) + w3 * bf16_to_f32((unsigned short)v3[j]);
                }
                c0 = p0; c1 = p1; c2 = p2; c3 = p3; i = i4;
            }
            {   // masked tail
                bool m0 = i < cnt, m1 = i + 1 < cnt, m2 = i + 2 < cnt, m3 = i + 3 < cnt;
                float e0 = el[c0], e1 = el[c1], e2 = el[c2], e3 = el[c3];
                bf16x8 v0 = *(const bf16x8*)(h2b + (size_t)c0 * C2 + sub * 8);
                bf16x8 v1 = *(const bf16x8*)(h2b + (size_t)c1 * C2 + sub * 8);
                bf16x8 v2 = *(const bf16x8*)(h2b + (size_t)c2 * C2 + sub * 8);
                bf16x8 v3 = *(const bf16x8*)(h2b + (size_t)c3 * C2 + sub * 8);
                e0 += erd; e1 += erd; e2 += erd; e3 += erd;
                e0 = e0 > 0.f ? e0 : NEG * e0;
                e1 = e1 > 0.f ? e1 : NEG * e1;
                e2 = e2 > 0.f ? e2 : NEG * e2;
                e3 = e3 > 0.f ? e3 : NEG * e3;
                float w0 = m0 ? __expf(e0) : 0.f;
                float w1 = m1 ? __expf(e1) : 0.f;
                float w2 = m2 ? __expf(e2) : 0.f;
                float w3 = m3 ? __expf(e3) : 0.f;
                s += (w0 + w1) + (w2 + w3);
#pragma unroll
                for (int j = 0; j < 8; j++) {
                    acc[j] += w0 * bf16_to_f32((unsigned short)v0[j]) + w1 * bf16_to_f32((unsigned short)v1[j]) +
                              w2 * bf16_to_f32((unsigned short)v2[j]) + w3 * bf16_to_f32((unsigned short)v3[j]);
                }
            }
        }
        float sinv = (s > 0.f) ? 1.f / s : 0.f;
        const float* bp = b2 + sub * 8;
#pragma unroll
        for (int j = 0; j < 8; j++) vals[j] = acc[j] * sinv + bp[j];
    } else {
#pragma unroll
        for (int j = 0; j < 8; j++) vals[j] = -1e30f;
    }
    float mx = vals[0];
#pragma unroll
    for (int j = 1; j < 8; j++) mx = fmaxf(mx, vals[j]);
#pragma unroll
    for (int off = 1; off < 8; off <<= 1) mx = fmaxf(mx, __shfl_xor(mx, off, 8));
    float se = 0.f;
#pragma unroll
    for (int j = 0; j < 8; j++) se += __expf(vals[j] - mx);
#pragma unroll
    for (int off = 1; off < 8; off <<= 1) se += __shfl_xor(se, off, 8);
    float ls = __logf(se) + mx;
    if (sub < 5) {
        float* op = out + (size_t)n * C2 + sub * 8;
        *(float4*)(op) = make_float4(vals[0] - ls, vals[1] - ls, vals[2] - ls, vals[3] - ls);
        *(float4*)(op + 4) = make_float4(vals[4] - ls, vals[5] - ls, vals[6] - ls, vals[7] - ls);
    }
}

extern "C" void kernel_launch(void* const* d_in, const int* in_sizes, int n_in,
                              void* d_out, int out_size, void* d_ws, size_t ws_size,
                              hipStream_t stream) {
    (void)n_in; (void)out_size; (void)ws_size;
    const float* x   = (const float*)d_in[0];
    const int*   src = (const int*)d_in[1];
    const int*   dst = (const int*)d_in[2];
    const float* W1  = (const float*)d_in[3];
    const float* al1 = (const float*)d_in[4];
    const float* ar1 = (const float*)d_in[5];
    const float* b1  = (const float*)d_in[6];
    const float* W2  = (const float*)d_in[7];
    const float* al2 = (const float*)d_in[8];
    const float* ar2 = (const float*)d_in[9];
    const float* b2  = (const float*)d_in[10];
    float* out = (float*)d_out;
    const int N = in_sizes[0] / IN_F;
    const int E = in_sizes[1];

    char* w = (char*)d_ws;
    auto alloc = [&](size_t bytes) -> char* {
        char* p = w;
        w += (bytes + 255) & ~(size_t)255;
        return p;
    };
    int* deg     = (int*)alloc((size_t)N * 4);
    int* rowp    = (int*)alloc((size_t)N * 4);
    int* cur     = (int*)alloc((size_t)N * 4);
    int* bsums   = (int*)alloc(512);
    int* csr_src = (int*)alloc((size_t)E * 4);
    unsigned short* wt_hi = (unsigned short*)alloc((size_t)IN_F * C1 * 2);
    unsigned short* wt_lo = (unsigned short*)alloc((size_t)IN_F * C1 * 2);
    unsigned short* w2t_hi = (unsigned short*)alloc((size_t)48 * 64 * 2);
    unsigned short* w2t_lo = (unsigned short*)alloc((size_t)48 * 64 * 2);
    unsigned short* hb    = (unsigned short*)alloc((size_t)N * C1 * 2);
    float* el1   = (float*)alloc((size_t)N * NH * 4);
    float* er1   = (float*)alloc((size_t)N * NH * 4);
    unsigned short* h2b = (unsigned short*)alloc((size_t)N * C2 * 2);
    float* el2   = (float*)alloc((size_t)N * 4);
    float* er2   = (float*)alloc((size_t)N * 4);

    hipMemsetAsync(deg, 0, (size_t)N * 4, stream);

    int ebl = (E + 255) / 256;
    int nb = (N + 1023) / 1024;
    hist_k<<<ebl, 256, 0, stream>>>(dst, deg, E);
    scan_local_k<<<nb, 1024, 0, stream>>>(deg, rowp, bsums, N);
    scan_add_k<<<nb, 1024, 0, stream>>>(rowp, cur, bsums, N, nb);
    scatter_k<<<ebl, 256, 0, stream>>>(src, dst, cur, csr_src, E);

    pre_k<<<(IN_F * C1 + 48 * 64 + 255) / 256, 256, 0, stream>>>(W1, W2, wt_hi, wt_lo, w2t_hi, w2t_lo);
    gemm1_mfma_k<<<(N + 63) / 64, 256, 0, stream>>>(x, wt_hi, wt_lo, al1, ar1, hb, el1, er1, N);
    l1_gemm2_k<<<(N + 63) / 64, 1024, 0, stream>>>(hb, el1, er1, rowp, deg, csr_src, b1,
                                                   w2t_hi, w2t_lo, al2, ar2, h2b, el2, er2, N);
    l2_fused_k<<<(N + 31) / 32, 256, 0, stream>>>(h2b, el2, er2, rowp, deg, csr_src, b2, out, N);
}

// Round 4
// 625.074 us; speedup vs baseline: 1.0030x; 1.0030x over previous
//
#include <hip/hip_runtime.h>
#include <cstdint>
#include <cstddef>

#define IN_F 512
#define C1 64      // H1*F1
#define NH 8
#define FD 8
#define C2 40
#define NEG 0.2f

typedef __attribute__((ext_vector_type(8))) short bf16x8;
typedef __attribute__((ext_vector_type(4))) float f32x4;

__device__ inline unsigned short f32_to_bf16_rne(float f) {
    unsigned int u = __float_as_uint(f);
    unsigned int r = (u + 0x7FFFu + ((u >> 16) & 1u)) >> 16;
    return (unsigned short)r;
}
__device__ inline float bf16_to_f32(unsigned short s) {
    return __uint_as_float(((unsigned int)s) << 16);
}

// ---------------- CSR build ----------------
// fire-and-forget histogram, 4 edges/thread
__global__ __launch_bounds__(256) void hist_k(const int* __restrict__ dst, int* __restrict__ deg, int E) {
    int base = blockIdx.x * 1024 + threadIdx.x;
#pragma unroll
    for (int j = 0; j < 4; j++) {
        int e = base + j * 256;
        if (e < E) atomicAdd(&deg[dst[e]], 1);
    }
}

__global__ __launch_bounds__(1024) void scan_local_k(const int* __restrict__ deg, int* __restrict__ rowp,
                                                     int* __restrict__ bsums, int n) {
    __shared__ int tmp[1024];
    int tx = threadIdx.x;
    int i = blockIdx.x * 1024 + tx;
    int v = (i < n) ? deg[i] : 0;
    tmp[tx] = v;
    __syncthreads();
    for (int d = 1; d < 1024; d <<= 1) {
        int t = (tx >= d) ? tmp[tx - d] : 0;
        __syncthreads();
        tmp[tx] += t;
        __syncthreads();
    }
    if (i < n) rowp[i] = tmp[tx] - v;   // exclusive within block
    if (tx == 1023) bsums[blockIdx.x] = tmp[tx];   // raw block total
}

// fused: each block reduces bsums[0..blockIdx.x) itself (nb <= 128); also emits cursor copy
__global__ __launch_bounds__(1024) void scan_add_k(int* rowp, int* __restrict__ cur,
                                                   const int* __restrict__ bsums, int n, int nb) {
    __shared__ int red[128];
    int tx = threadIdx.x;
    if (tx < 128) red[tx] = (tx < blockIdx.x && tx < nb) ? bsums[tx] : 0;
    __syncthreads();
    if (tx < 64) red[tx] += red[tx + 64];
    __syncthreads();
    if (tx < 32) red[tx] += red[tx + 32];
    __syncthreads();
    if (tx < 16) red[tx] += red[tx + 16];
    __syncthreads();
    if (tx < 8) red[tx] += red[tx + 8];
    __syncthreads();
    if (tx < 4) red[tx] += red[tx + 4];
    __syncthreads();
    if (tx < 2) red[tx] += red[tx + 2];
    __syncthreads();
    if (tx == 0) red[0] += red[1];
    __syncthreads();
    int off = red[0];
    int i = blockIdx.x * 1024 + tx;
    if (i < n) {
        int r = rowp[i] + off;
        rowp[i] = r;
        cur[i] = r;
    }
}

// scatter with 4 independent atomic-return chains per thread (latency hiding)
__global__ __launch_bounds__(256) void scatter_k(const int* __restrict__ src, const int* __restrict__ dst,
                                                 int* __restrict__ cur, int* __restrict__ csr_src, int E) {
    int base = blockIdx.x * 1024 + threadIdx.x;
    int e3 = base + 768;
    if (e3 < E) {
        int d0 = dst[base], d1 = dst[base + 256], d2 = dst[base + 512], d3 = dst[e3];
        int s0 = src[base], s1 = src[base + 256], s2 = src[base + 512], s3 = src[e3];
        int p0 = atomicAdd(&cur[d0], 1);
        int p1 = atomicAdd(&cur[d1], 1);
        int p2 = atomicAdd(&cur[d2], 1);
        int p3 = atomicAdd(&cur[d3], 1);
        csr_src[p0] = s0;
        csr_src[p1] = s1;
        csr_src[p2] = s2;
        csr_src[p3] = s3;
    } else {
#pragma unroll
        for (int j = 0; j < 4; j++) {
            int e = base + j * 256;
            if (e < E) {
                int p = atomicAdd(&cur[dst[e]], 1);
                csr_src[p] = src[e];
            }
        }
    }
}

// ---------------- preconvert: W1 -> wt_hi/lo[col][k], W2^T -> w2t_hi/lo[48][64] split-bf16 ----------------
__global__ __launch_bounds__(256) void pre_k(const float* __restrict__ W1, const float* __restrict__ W2,
                                             unsigned short* __restrict__ wt_hi, unsigned short* __restrict__ wt_lo,
                                             unsigned short* __restrict__ w2t_hi, unsigned short* __restrict__ w2t_lo) {
    int id = blockIdx.x * 256 + threadIdx.x;
    if (id < IN_F * C1) {
        int col = id & (C1 - 1);
        int k = id >> 6;
        float w = W1[id];
        unsigned short hb = f32_to_bf16_rne(w);
        unsigned short lb = f32_to_bf16_rne(w - bf16_to_f32(hb));
        wt_hi[(size_t)col * IN_F + k] = hb;
        wt_lo[(size_t)col * IN_F + k] = lb;
    } else {
        int id2 = id - IN_F * C1;
        if (id2 < 48 * 64) {
            int c = id2 >> 6, k = id2 & 63;
            float w = (c < C2) ? W2[(size_t)k * C2 + c] : 0.f;
            unsigned short hb = f32_to_bf16_rne(w);
            unsigned short lb = f32_to_bf16_rne(w - bf16_to_f32(hb));
            w2t_hi[c * 64 + k] = hb;
            w2t_lo[c * 64 + k] = lb;
        }
    }
}

// ---------------- GEMM1 via split-bf16 MFMA; epilogue emits bf16 h rows + fused attn1 ----------------
__global__ __launch_bounds__(256) void gemm1_mfma_k(const float* __restrict__ x,
                                                    const unsigned short* __restrict__ wt_hi,
                                                    const unsigned short* __restrict__ wt_lo,
                                                    const float* __restrict__ al, const float* __restrict__ ar,
                                                    unsigned short* __restrict__ hb_out,
                                                    float* __restrict__ el, float* __restrict__ er, int N) {
    __shared__ alignas(16) unsigned short wlds[2][8192];   // 32 KB
    const int tid = threadIdx.x;
    const int wave = tid >> 6, lane = tid & 63;
    const int m = lane & 15, q = lane >> 4;
    const int row = blockIdx.x * 64 + wave * 16 + m;
    const int row_c = row < N ? row : N - 1;
    const float* xp = x + (size_t)row_c * IN_F + q * 8;

    f32x4 acc[4];
#pragma unroll
    for (int ct = 0; ct < 4; ct++) acc[ct] = (f32x4){0.f, 0.f, 0.f, 0.f};
    float4 xr[2][4];

#define WLOAD(c, buf)                                                                              \
    {                                                                                              \
        _Pragma("unroll") for (int j_ = 0; j_ < 4; j_++) {                                         \
            int slot_ = j_ * 256 + wave * 64 + lane;                                               \
            const unsigned short* gbase_ = (slot_ < 512) ? wt_hi : wt_lo;                          \
            int s_ = slot_ & 511;                                                                  \
            int col_ = s_ & 63, kq_ = s_ >> 6;                                                     \
            const unsigned short* g_ = gbase_ + (size_t)col_ * IN_F + (c) * 64 + kq_ * 8;          \
            unsigned short* l_ = &wlds[buf][0] + (size_t)(j_ * 256 + wave * 64) * 8;               \
            __builtin_amdgcn_global_load_lds((const __attribute__((address_space(1))) unsigned int*)g_, \
                                             (__attribute__((address_space(3))) unsigned int*)l_,  \
                                             16, 0, 0);                                            \
        }                                                                                          \
    }
#define XLOAD(c, r)                                  \
    {                                                \
        const float* xsrc_ = xp + (c) * 64;          \
        (r)[0] = *(const float4*)(xsrc_);            \
        (r)[1] = *(const float4*)(xsrc_ + 4);        \
        (r)[2] = *(const float4*)(xsrc_ + 32);       \
        (r)[3] = *(const float4*)(xsrc_ + 36);       \
    }

    WLOAD(0, 0);
    XLOAD(0, xr[0]);

    for (int c = 0; c < 8; c++) {
        int p = c & 1;
        __syncthreads();
        if (c < 7) {
            WLOAD(c + 1, p ^ 1);
            XLOAD(c + 1, xr[p ^ 1]);
        }
#pragma unroll
        for (int ki = 0; ki < 2; ki++) {
            float f[8];
            f[0] = xr[p][ki * 2].x; f[1] = xr[p][ki * 2].y; f[2] = xr[p][ki * 2].z; f[3] = xr[p][ki * 2].w;
            f[4] = xr[p][ki * 2 + 1].x; f[5] = xr[p][ki * 2 + 1].y; f[6] = xr[p][ki * 2 + 1].z; f[7] = xr[p][ki * 2 + 1].w;
            unsigned int u[8], lu[8];
#pragma unroll
            for (int j = 0; j < 8; j++) u[j] = __float_as_uint(f[j]);
            union { uint4 u4; bf16x8 v; } H, L;
            H.u4.x = __builtin_amdgcn_perm(u[1], u[0], 0x07060302u);
            H.u4.y = __builtin_amdgcn_perm(u[3], u[2], 0x07060302u);
            H.u4.z = __builtin_amdgcn_perm(u[5], u[4], 0x07060302u);
            H.u4.w = __builtin_amdgcn_perm(u[7], u[6], 0x07060302u);
#pragma unroll
            for (int j = 0; j < 8; j++)
                lu[j] = __float_as_uint(f[j] - __uint_as_float(u[j] & 0xFFFF0000u));
            L.u4.x = __builtin_amdgcn_perm(lu[1], lu[0], 0x07060302u);
            L.u4.y = __builtin_amdgcn_perm(lu[3], lu[2], 0x07060302u);
            L.u4.z = __builtin_amdgcn_perm(lu[5], lu[4], 0x07060302u);
            L.u4.w = __builtin_amdgcn_perm(lu[7], lu[6], 0x07060302u);
            int kq = ki * 4 + q;
#pragma unroll
            for (int ct = 0; ct < 4; ct++) {
                int slot = kq * 64 + ct * 16 + m;
                bf16x8 bh = *(const bf16x8*)&wlds[p][slot * 8];
                bf16x8 bl = *(const bf16x8*)&wlds[p][4096 + slot * 8];
                acc[ct] = __builtin_amdgcn_mfma_f32_16x16x32_bf16(H.v, bh, acc[ct], 0, 0, 0);
                acc[ct] = __builtin_amdgcn_mfma_f32_16x16x32_bf16(L.v, bh, acc[ct], 0, 0, 0);
                acc[ct] = __builtin_amdgcn_mfma_f32_16x16x32_bf16(H.v, bl, acc[ct], 0, 0, 0);
            }
        }
    }
    int rbase = blockIdx.x * 64 + wave * 16 + q * 4;
#pragma unroll
    for (int r = 0; r < 4; r++) {
        int ro = rbase + r;
        if (ro < N) {
#pragma unroll
            for (int ct = 0; ct < 4; ct++)
                hb_out[(size_t)ro * C1 + ct * 16 + m] = f32_to_bf16_rne(acc[ct][r]);
        }
    }

    // ----- fused attn1: stash fp32 h into LDS, compute el/er for this block's 64 rows -----
    __syncthreads();   // all waves done reading wlds before reuse
    float* hst = (float*)&wlds[0][0];   // [64][69] floats = 17.6 KB
    {
        int rr = wave * 16 + q * 4;
#pragma unroll
        for (int r = 0; r < 4; r++)
#pragma unroll
            for (int ct = 0; ct < 4; ct++)
                hst[(rr + r) * 69 + ct * 16 + m] = acc[ct][r];
    }
    __syncthreads();
    for (int id = tid; id < 512; id += 256) {
        int r = id >> 3, hd = id & 7;
        int nn = blockIdx.x * 64 + r;
        if (nn < N) {
            float e_l = 0.f, e_r = 0.f;
#pragma unroll
            for (int f = 0; f < 8; f++) {
                float v = hst[r * 69 + hd * 8 + f];
                e_l += v * al[hd * 8 + f];
                e_r += v * ar[hd * 8 + f];
            }
            el[(size_t)nn * NH + hd] = e_l;
            er[(size_t)nn * NH + hd] = e_r;
        }
    }
#undef WLOAD
#undef XLOAD
}

// ---------------- layer1: one wave per node, quarter-wave = edge slot, uint2 hb gathers, csr prefetch ----
// lane L: quarter q=L>>4 handles edges i+q; f=L&15 owns features 4f..4f+3 (head f>>1).
__global__ __launch_bounds__(256) void l1_wave_k(const unsigned short* __restrict__ hb,
                                                 const float* __restrict__ el, const float* __restrict__ er,
                                                 const int* __restrict__ rowp, const int* __restrict__ deg,
                                                 const int* __restrict__ csr_src, const float* __restrict__ b1,
                                                 float* __restrict__ h1out, int N) {
    int n = (blockIdx.x * 256 + threadIdx.x) >> 6;   // node = global wave id
    if (n >= N) return;
    int lane = threadIdx.x & 63;
    int q = lane >> 4;
    int f = lane & 15;
    int hd = f >> 1;
    int start = rowp[n], cnt = deg[n];
    float erd = er[(size_t)n * NH + hd];
    const uint2* hb64 = (const uint2*)hb;   // row = 16 uint2 (64 bf16)
    const int* cp = csr_src + start;
    float a0 = 0.f, a1 = 0.f, a2 = 0.f, a3 = 0.f, s = 0.f;
    if (cnt > 0) {
        int lastc = cnt - 1;
        int c0 = cp[(q < cnt) ? q : lastc];
        int c1 = cp[(4 + q < cnt) ? 4 + q : lastc];
        int i = 0;
        while (i + 8 < cnt) {
            int i8 = i + 8;
            int c2 = cp[(i8 + q < cnt) ? i8 + q : lastc];
            int c3 = cp[(i8 + 4 + q < cnt) ? i8 + 4 + q : lastc];
            float e0 = el[(size_t)c0 * NH + hd] + erd;
            float e1 = el[(size_t)c1 * NH + hd] + erd;
            uint2 v0 = hb64[(size_t)c0 * 16 + f];
            uint2 v1 = hb64[(size_t)c1 * 16 + f];
            e0 = e0 > 0.f ? e0 : NEG * e0;
            e1 = e1 > 0.f ? e1 : NEG * e1;
            float w0 = __expf(e0), w1 = __expf(e1);
            s += w0 + w1;
            a0 += w0 * __uint_as_float(v0.x << 16) + w1 * __uint_as_float(v1.x << 16);
            a1 += w0 * __uint_as_float(v0.x & 0xFFFF0000u) + w1 * __uint_as_float(v1.x & 0xFFFF0000u);
            a2 += w0 * __uint_as_float(v0.y << 16) + w1 * __uint_as_float(v1.y << 16);
            a3 += w0 * __uint_as_float(v0.y & 0xFFFF0000u) + w1 * __uint_as_float(v1.y & 0xFFFF0000u);
            c0 = c2; c1 = c3; i = i8;
        }
        {   // masked tail: edges i+q and i+4+q
            bool m0 = (i + q) < cnt, m1 = (i + 4 + q) < cnt;
            float e0 = el[(size_t)c0 * NH + hd] + erd;
            float e1 = el[(size_t)c1 * NH + hd] + erd;
            uint2 v0 = hb64[(size_t)c0 * 16 + f];
            uint2 v1 = hb64[(size_t)c1 * 16 + f];
            e0 = e0 > 0.f ? e0 : NEG * e0;
            e1 = e1 > 0.f ? e1 : NEG * e1;
            float w0 = m0 ? __expf(e0) : 0.f;
            float w1 = m1 ? __expf(e1) : 0.f;
            s += w0 + w1;
            a0 += w0 * __uint_as_float(v0.x << 16) + w1 * __uint_as_float(v1.x << 16);
            a1 += w0 * __uint_as_float(v0.x & 0xFFFF0000u) + w1 * __uint_as_float(v1.x & 0xFFFF0000u);
            a2 += w0 * __uint_as_float(v0.y << 16) + w1 * __uint_as_float(v1.y << 16);
            a3 += w0 * __uint_as_float(v0.y & 0xFFFF0000u) + w1 * __uint_as_float(v1.y & 0xFFFF0000u);
        }
    }
    // cross-quarter reduce
    a0 += __shfl_xor(a0, 16); a0 += __shfl_xor(a0, 32);
    a1 += __shfl_xor(a1, 16); a1 += __shfl_xor(a1, 32);
    a2 += __shfl_xor(a2, 16); a2 += __shfl_xor(a2, 32);
    a3 += __shfl_xor(a3, 16); a3 += __shfl_xor(a3, 32);
    s  += __shfl_xor(s, 16);  s  += __shfl_xor(s, 32);
    float sinv = (s > 0.f) ? 1.f / s : 0.f;
    float4 bv = *(const float4*)(b1 + f * 4);
    float o0 = a0 * sinv + bv.x;
    float o1 = a1 * sinv + bv.y;
    float o2 = a2 * sinv + bv.z;
    float o3 = a3 * sinv + bv.w;
    o0 = o0 > 0.f ? o0 : (__expf(o0) - 1.f);
    o1 = o1 > 0.f ? o1 : (__expf(o1) - 1.f);
    o2 = o2 > 0.f ? o2 : (__expf(o2) - 1.f);
    o3 = o3 > 0.f ? o3 : (__expf(o3) - 1.f);
    if (q == 0) *(float4*)(h1out + (size_t)n * C1 + f * 4) = make_float4(o0, o1, o2, o3);
}

// ---------------- GEMM2 via split-bf16 MFMA + attn2: h2b[N,40] bf16, el2/er2 fp32 ----------------
__global__ __launch_bounds__(256) void gemm2_attn2_k(const float* __restrict__ h1,
                                                     const unsigned short* __restrict__ w2t_hi,
                                                     const unsigned short* __restrict__ w2t_lo,
                                                     const float* __restrict__ al2, const float* __restrict__ ar2,
                                                     unsigned short* __restrict__ h2b, float* __restrict__ el2,
                                                     float* __restrict__ er2, int N) {
    __shared__ float h2s[64][49];   // 12.5 KB, stride 49 kills bank conflicts on attn2 reads
    __shared__ float a2s[2 * C2];
    int t = threadIdx.x;
    int wave = t >> 6, lane = t & 63;
    int m = lane & 15, q = lane >> 4;
    int n0 = blockIdx.x * 64;
    if (t < C2) a2s[t] = al2[t];
    else if (t < 2 * C2) a2s[t] = ar2[t - C2];
    int row = n0 + wave * 16 + m;
    int row_c = row < N ? row : N - 1;
    const float* hp = h1 + (size_t)row_c * C1 + q * 8;
    f32x4 acc[3];
#pragma unroll
    for (int ct = 0; ct < 3; ct++) acc[ct] = (f32x4){0.f, 0.f, 0.f, 0.f};
#pragma unroll
    for (int ks = 0; ks < 2; ks++) {
        float4 r0 = *(const float4*)(hp + ks * 32);
        float4 r1 = *(const float4*)(hp + ks * 32 + 4);
        float f[8];
        f[0] = r0.x; f[1] = r0.y; f[2] = r0.z; f[3] = r0.w;
        f[4] = r1.x; f[5] = r1.y; f[6] = r1.z; f[7] = r1.w;
        unsigned int u[8], lu[8];
#pragma unroll
        for (int j = 0; j < 8; j++) u[j] = __float_as_uint(f[j]);
        union { uint4 u4; bf16x8 v; } H, L;
        H.u4.x = __builtin_amdgcn_perm(u[1], u[0], 0x07060302u);
        H.u4.y = __builtin_amdgcn_perm(u[3], u[2], 0x07060302u);
        H.u4.z = __builtin_amdgcn_perm(u[5], u[4], 0x07060302u);
        H.u4.w = __builtin_amdgcn_perm(u[7], u[6], 0x07060302u);
#pragma unroll
        for (int j = 0; j < 8; j++)
            lu[j] = __float_as_uint(f[j] - __uint_as_float(u[j] & 0xFFFF0000u));
        L.u4.x = __builtin_amdgcn_perm(lu[1], lu[0], 0x07060302u);
        L.u4.y = __builtin_amdgcn_perm(lu[3], lu[2], 0x07060302u);
        L.u4.z = __builtin_amdgcn_perm(lu[5], lu[4], 0x07060302u);
        L.u4.w = __builtin_amdgcn_perm(lu[7], lu[6], 0x07060302u);
        int kb = ks * 32 + q * 8;
#pragma unroll
        for (int ct = 0; ct < 3; ct++) {
            int col = ct * 16 + m;
            bf16x8 bh = *(const bf16x8*)(w2t_hi + col * 64 + kb);
            bf16x8 bl = *(const bf16x8*)(w2t_lo + col * 64 + kb);
            acc[ct] = __builtin_amdgcn_mfma_f32_16x16x32_bf16(H.v, bh, acc[ct], 0, 0, 0);
            acc[ct] = __builtin_amdgcn_mfma_f32_16x16x32_bf16(L.v, bh, acc[ct], 0, 0, 0);
            acc[ct] = __builtin_amdgcn_mfma_f32_16x16x32_bf16(H.v, bl, acc[ct], 0, 0, 0);
        }
    }
    int rl = wave * 16 + q * 4;
#pragma unroll
    for (int ct = 0; ct < 3; ct++)
#pragma unroll
        for (int r = 0; r < 4; r++) h2s[rl + r][ct * 16 + m] = acc[ct][r];
    __syncthreads();
    // write unpadded bf16 rows: 20 dwords per row
    unsigned int* h2d = (unsigned int*)h2b;
    for (int o = t; o < 64 * 20; o += 256) {
        int r = o / 20, cd = o % 20;
        int nn = n0 + r;
        if (nn < N) {
            unsigned int lo16 = f32_to_bf16_rne(h2s[r][cd * 2]);
            unsigned int hi16 = f32_to_bf16_rne(h2s[r][cd * 2 + 1]);
            h2d[(size_t)nn * 20 + cd] = lo16 | (hi16 << 16);
        }
    }
    if (t < 64) {
        int nn = n0 + t;
        if (nn < N) {
            float e_l = 0.f, e_r = 0.f;
#pragma unroll
            for (int c = 0; c < C2; c++) {
                float v = h2s[t][c];
                e_l += v * a2s[c];
                e_r += v * a2s[C2 + c];
            }
            el2[nn] = e_l;
            er2[nn] = e_r;
        }
    }
}

// ---------------- layer2: 8 lanes/node; lanes sub<5 gather (80 B/row), csr prefetch ----------------
__global__ __launch_bounds__(256) void l2_fused_k(const unsigned short* __restrict__ h2b,
                                                  const float* __restrict__ el, const float* __restrict__ er,
                                                  const int* __restrict__ rowp, const int* __restrict__ deg,
                                                  const int* __restrict__ csr_src, const float* __restrict__ b2,
                                                  float* __restrict__ out, int N) {
    int tid = threadIdx.x;
    int n = blockIdx.x * 32 + (tid >> 3);
    int sub = tid & 7;
    if (n >= N) return;
    float vals[8];
    if (sub < 5) {
        int start = rowp[n], cnt = deg[n];
        float erd = er[n];
        float s = 0.f;
        float acc[8];
#pragma unroll
        for (int j = 0; j < 8; j++) acc[j] = 0.f;
        const int* cp = csr_src + start;
        if (cnt > 0) {
            int last = cnt - 1;
            int c0 = cp[0];
            int c1 = cp[1 < cnt ? 1 : last];
            int c2 = cp[2 < cnt ? 2 : last];
            int c3 = cp[3 < cnt ? 3 : last];
            int i = 0;
            while (i + 4 < cnt) {
                int i4 = i + 4;
                int p0 = cp[i4];
                int p1 = cp[(i4 + 1 < cnt) ? i4 + 1 : last];
                int p2 = cp[(i4 + 2 < cnt) ? i4 + 2 : last];
                int p3 = cp[(i4 + 3 < cnt) ? i4 + 3 : last];
                float e0 = el[c0], e1 = el[c1], e2 = el[c2], e3 = el[c3];
                bf16x8 v0 = *(const bf16x8*)(h2b + (size_t)c0 * C2 + sub * 8);
                bf16x8 v1 = *(const bf16x8*)(h2b + (size_t)c1 * C2 + sub * 8);
                bf16x8 v2 = *(const bf16x8*)(h2b + (size_t)c2 * C2 + sub * 8);
                bf16x8 v3 = *(const bf16x8*)(h2b + (size_t)c3 * C2 + sub * 8);
                e0 += erd; e1 += erd; e2 += erd; e3 += erd;
                e0 = e0 > 0.f ? e0 : NEG * e0;
                e1 = e1 > 0.f ? e1 : NEG * e1;
                e2 = e2 > 0.f ? e2 : NEG * e2;
                e3 = e3 > 0.f ? e3 : NEG * e3;
                float w0 = __expf(e0), w1 = __expf(e1), w2 = __expf(e2), w3 = __expf(e3);
                s += (w0 + w1) + (w2 + w3);
#pragma unroll
                for (int j = 0; j < 8; j++) {
                    acc[j] += w0 * bf16_to_f32((unsigned short)v0[j]) + w1 * bf16_to_f32((unsigned short)v1[j]) +
                              w2 * bf16_to_f32((unsigned short)v2[j]) + w3 * bf16_to_f32((unsigned short)v3[j]);
                }
                c0 = p0; c1 = p1; c2 = p2; c3 = p3; i = i4;
            }
            {   // masked tail
                bool m0 = i < cnt, m1 = i + 1 < cnt, m2 = i + 2 < cnt, m3 = i + 3 < cnt;
                float e0 = el[c0], e1 = el[c1], e2 = el[c2], e3 = el[c3];
                bf16x8 v0 = *(const bf16x8*)(h2b + (size_t)c0 * C2 + sub * 8);
                bf16x8 v1 = *(const bf16x8*)(h2b + (size_t)c1 * C2 + sub * 8);
                bf16x8 v2 = *(const bf16x8*)(h2b + (size_t)c2 * C2 + sub * 8);
                bf16x8 v3 = *(const bf16x8*)(h2b + (size_t)c3 * C2 + sub * 8);
                e0 += erd; e1 += erd; e2 += erd; e3 += erd;
                e0 = e0 > 0.f ? e0 : NEG * e0;
                e1 = e1 > 0.f ? e1 : NEG * e1;
                e2 = e2 > 0.f ? e2 : NEG * e2;
                e3 = e3 > 0.f ? e3 : NEG * e3;
                float w0 = m0 ? __expf(e0) : 0.f;
                float w1 = m1 ? __expf(e1) : 0.f;
                float w2 = m2 ? __expf(e2) : 0.f;
                float w3 = m3 ? __expf(e3) : 0.f;
                s += (w0 + w1) + (w2 + w3);
#pragma unroll
                for (int j = 0; j < 8; j++) {
                    acc[j] += w0 * bf16_to_f32((unsigned short)v0[j]) + w1 * bf16_to_f32((unsigned short)v1[j]) +
                              w2 * bf16_to_f32((unsigned short)v2[j]) + w3 * bf16_to_f32((unsigned short)v3[j]);
                }
            }
        }
        float sinv = (s > 0.f) ? 1.f / s : 0.f;
        const float* bp = b2 + sub * 8;
#pragma unroll
        for (int j = 0; j < 8; j++) vals[j] = acc[j] * sinv + bp[j];
    } else {
#pragma unroll
        for (int j = 0; j < 8; j++) vals[j] = -1e30f;
    }
    float mx = vals[0];
#pragma unroll
    for (int j = 1; j < 8; j++) mx = fmaxf(mx, vals[j]);
#pragma unroll
    for (int off = 1; off < 8; off <<= 1) mx = fmaxf(mx, __shfl_xor(mx, off, 8));
    float se = 0.f;
#pragma unroll
    for (int j = 0; j < 8; j++) se += __expf(vals[j] - mx);
#pragma unroll
    for (int off = 1; off < 8; off <<= 1) se += __shfl_xor(se, off, 8);
    float ls = __logf(se) + mx;
    if (sub < 5) {
        float* op = out + (size_t)n * C2 + sub * 8;
        *(float4*)(op) = make_float4(vals[0] - ls, vals[1] - ls, vals[2] - ls, vals[3] - ls);
        *(float4*)(op + 4) = make_float4(vals[4] - ls, vals[5] - ls, vals[6] - ls, vals[7] - ls);
    }
}

extern "C" void kernel_launch(void* const* d_in, const int* in_sizes, int n_in,
                              void* d_out, int out_size, void* d_ws, size_t ws_size,
                              hipStream_t stream) {
    (void)n_in; (void)out_size; (void)ws_size;
    const float* x   = (const float*)d_in[0];
    const int*   src = (const int*)d_in[1];
    const int*   dst = (const int*)d_in[2];
    const float* W1  = (const float*)d_in[3];
    const float* al1 = (const float*)d_in[4];
    const float* ar1 = (const float*)d_in[5];
    const float* b1  = (const float*)d_in[6];
    const float* W2  = (const float*)d_in[7];
    const float* al2 = (const float*)d_in[8];
    const float* ar2 = (const float*)d_in[9];
    const float* b2  = (const float*)d_in[10];
    float* out = (float*)d_out;
    const int N = in_sizes[0] / IN_F;
    const int E = in_sizes[1];

    char* w = (char*)d_ws;
    auto alloc = [&](size_t bytes) -> char* {
        char* p = w;
        w += (bytes + 255) & ~(size_t)255;
        return p;
    };
    int* deg     = (int*)alloc((size_t)N * 4);
    int* rowp    = (int*)alloc((size_t)N * 4);
    int* cur     = (int*)alloc((size_t)N * 4);
    int* bsums   = (int*)alloc(512);
    int* csr_src = (int*)alloc((size_t)E * 4);
    unsigned short* wt_hi = (unsigned short*)alloc((size_t)IN_F * C1 * 2);
    unsigned short* wt_lo = (unsigned short*)alloc((size_t)IN_F * C1 * 2);
    unsigned short* w2t_hi = (unsigned short*)alloc((size_t)48 * 64 * 2);
    unsigned short* w2t_lo = (unsigned short*)alloc((size_t)48 * 64 * 2);
    unsigned short* hb    = (unsigned short*)alloc((size_t)N * C1 * 2);
    float* el1   = (float*)alloc((size_t)N * NH * 4);
    float* er1   = (float*)alloc((size_t)N * NH * 4);
    float* h1    = (float*)alloc((size_t)N * C1 * 4);
    unsigned short* h2b = (unsigned short*)alloc((size_t)N * C2 * 2);
    float* el2   = (float*)alloc((size_t)N * 4);
    float* er2   = (float*)alloc((size_t)N * 4);

    hipMemsetAsync(deg, 0, (size_t)N * 4, stream);

    int ebl4 = (E + 1023) / 1024;
    int nb = (N + 1023) / 1024;
    hist_k<<<ebl4, 256, 0, stream>>>(dst, deg, E);
    scan_local_k<<<nb, 1024, 0, stream>>>(deg, rowp, bsums, N);
    scan_add_k<<<nb, 1024, 0, stream>>>(rowp, cur, bsums, N, nb);
    scatter_k<<<ebl4, 256, 0, stream>>>(src, dst, cur, csr_src, E);

    pre_k<<<(IN_F * C1 + 48 * 64 + 255) / 256, 256, 0, stream>>>(W1, W2, wt_hi, wt_lo, w2t_hi, w2t_lo);
    gemm1_mfma_k<<<(N + 63) / 64, 256, 0, stream>>>(x, wt_hi, wt_lo, al1, ar1, hb, el1, er1, N);
    l1_wave_k<<<(N * 64 + 255) / 256, 256, 0, stream>>>(hb, el1, er1, rowp, deg, csr_src, b1, h1, N);
    gemm2_attn2_k<<<(N + 63) / 64, 256, 0, stream>>>(h1, w2t_hi, w2t_lo, al2, ar2, h2b, el2, er2, N);
    l2_fused_k<<<(N + 31) / 32, 256, 0, stream>>>(h2b, el2, er2, rowp, deg, csr_src, b2, out, N);
}

// Round 5
// 544.785 us; speedup vs baseline: 1.1509x; 1.1474x over previous
//
#include <hip/hip_runtime.h>
#include <cstdint>
#include <cstddef>

#define IN_F 512
#define C1 64      // H1*F1
#define NH 8
#define FD 8
#define C2 40
#define NEG 0.2f

typedef __attribute__((ext_vector_type(8))) short bf16x8;
typedef __attribute__((ext_vector_type(4))) float f32x4;

__device__ inline unsigned short f32_to_bf16_rne(float f) {
    unsigned int u = __float_as_uint(f);
    unsigned int r = (u + 0x7FFFu + ((u >> 16) & 1u)) >> 16;
    return (unsigned short)r;
}
__device__ inline float bf16_to_f32(unsigned short s) {
    return __uint_as_float(((unsigned int)s) << 16);
}

// ---------------- fused: histogram (pos-based, coalesced dependent store) + weight preconvert ----------------
__global__ __launch_bounds__(256) void hist_pre_k(const int* __restrict__ dst, int* __restrict__ deg,
                                                  int* __restrict__ pos, int E, int HB,
                                                  const float* __restrict__ W1, const float* __restrict__ W2,
                                                  unsigned short* __restrict__ wt_hi, unsigned short* __restrict__ wt_lo,
                                                  unsigned short* __restrict__ w2t_hi, unsigned short* __restrict__ w2t_lo) {
    if ((int)blockIdx.x < HB) {
        int base = blockIdx.x * 1024 + threadIdx.x;
#pragma unroll
        for (int j = 0; j < 4; j++) {
            int e = base + j * 256;
            if (e < E) pos[e] = atomicAdd(&deg[dst[e]], 1);
        }
        return;
    }
    int id = (blockIdx.x - HB) * 256 + threadIdx.x;
    if (id < IN_F * C1) {
        int col = id & (C1 - 1);
        int k = id >> 6;
        float w = W1[id];
        unsigned short hb = f32_to_bf16_rne(w);
        unsigned short lb = f32_to_bf16_rne(w - bf16_to_f32(hb));
        wt_hi[(size_t)col * IN_F + k] = hb;
        wt_lo[(size_t)col * IN_F + k] = lb;
    } else {
        int id2 = id - IN_F * C1;
        if (id2 < 48 * 64) {
            int c = id2 >> 6, k = id2 & 63;
            float w = (c < C2) ? W2[(size_t)k * C2 + c] : 0.f;
            unsigned short hb = f32_to_bf16_rne(w);
            unsigned short lb = f32_to_bf16_rne(w - bf16_to_f32(hb));
            w2t_hi[c * 64 + k] = hb;
            w2t_lo[c * 64 + k] = lb;
        }
    }
}

__global__ __launch_bounds__(1024) void scan_local_k(const int* __restrict__ deg, int* __restrict__ rowp,
                                                     int* __restrict__ bsums, int n) {
    __shared__ int tmp[1024];
    int tx = threadIdx.x;
    int i = blockIdx.x * 1024 + tx;
    int v = (i < n) ? deg[i] : 0;
    tmp[tx] = v;
    __syncthreads();
    for (int d = 1; d < 1024; d <<= 1) {
        int t = (tx >= d) ? tmp[tx - d] : 0;
        __syncthreads();
        tmp[tx] += t;
        __syncthreads();
    }
    if (i < n) rowp[i] = tmp[tx] - v;   // exclusive within block
    if (tx == 1023) bsums[blockIdx.x] = tmp[tx];   // raw block total
}

// fused: each block reduces bsums[0..blockIdx.x) itself (nb <= 128)
__global__ __launch_bounds__(1024) void scan_add_k(int* rowp, const int* __restrict__ bsums, int n, int nb) {
    __shared__ int red[128];
    int tx = threadIdx.x;
    if (tx < 128) red[tx] = (tx < blockIdx.x && tx < nb) ? bsums[tx] : 0;
    __syncthreads();
    if (tx < 64) red[tx] += red[tx + 64];
    __syncthreads();
    if (tx < 32) red[tx] += red[tx + 32];
    __syncthreads();
    if (tx < 16) red[tx] += red[tx + 16];
    __syncthreads();
    if (tx < 8) red[tx] += red[tx + 8];
    __syncthreads();
    if (tx < 4) red[tx] += red[tx + 4];
    __syncthreads();
    if (tx < 2) red[tx] += red[tx + 2];
    __syncthreads();
    if (tx == 0) red[0] += red[1];
    __syncthreads();
    int off = red[0];
    int i = blockIdx.x * 1024 + tx;
    if (i < n) rowp[i] += off;
}

// ---------------- fused: CSR scatter (fire-and-forget writes) + GEMM1 split-bf16 MFMA ----------------
// blocks [0,SB): scatter 4 edges/thread. blocks [SB,..): gemm1 tile gb = blockIdx.x - SB.
// Scatter is latency/write-bound; gemm1 is MFMA-bound -> co-residency hides scatter.
__global__ __launch_bounds__(256) void scat_gemm1_k(const int* __restrict__ src, const int* __restrict__ dst,
                                                    const int* __restrict__ rowp, const int* __restrict__ pos,
                                                    int* __restrict__ csr_src, int E, int SB,
                                                    const float* __restrict__ x,
                                                    const unsigned short* __restrict__ wt_hi,
                                                    const unsigned short* __restrict__ wt_lo,
                                                    const float* __restrict__ al, const float* __restrict__ ar,
                                                    unsigned short* __restrict__ hb_out,
                                                    float* __restrict__ el, float* __restrict__ er, int N) {
    __shared__ alignas(16) unsigned short wlds[2][8192];   // 32 KB
    if ((int)blockIdx.x < SB) {
        int base = blockIdx.x * 1024 + threadIdx.x;
#pragma unroll
        for (int j = 0; j < 4; j++) {
            int e = base + j * 256;
            if (e < E) csr_src[rowp[dst[e]] + pos[e]] = src[e];
        }
        return;
    }
    const int gb = blockIdx.x - SB;
    const int tid = threadIdx.x;
    const int wave = tid >> 6, lane = tid & 63;
    const int m = lane & 15, q = lane >> 4;
    const int row = gb * 64 + wave * 16 + m;
    const int row_c = row < N ? row : N - 1;
    const float* xp = x + (size_t)row_c * IN_F + q * 8;

    f32x4 acc[4];
#pragma unroll
    for (int ct = 0; ct < 4; ct++) acc[ct] = (f32x4){0.f, 0.f, 0.f, 0.f};
    float4 xr[2][4];

#define WLOAD(c, buf)                                                                              \
    {                                                                                              \
        _Pragma("unroll") for (int j_ = 0; j_ < 4; j_++) {                                         \
            int slot_ = j_ * 256 + wave * 64 + lane;                                               \
            const unsigned short* gbase_ = (slot_ < 512) ? wt_hi : wt_lo;                          \
            int s_ = slot_ & 511;                                                                  \
            int col_ = s_ & 63, kq_ = s_ >> 6;                                                     \
            const unsigned short* g_ = gbase_ + (size_t)col_ * IN_F + (c) * 64 + kq_ * 8;          \
            unsigned short* l_ = &wlds[buf][0] + (size_t)(j_ * 256 + wave * 64) * 8;               \
            __builtin_amdgcn_global_load_lds((const __attribute__((address_space(1))) unsigned int*)g_, \
                                             (__attribute__((address_space(3))) unsigned int*)l_,  \
                                             16, 0, 0);                                            \
        }                                                                                          \
    }
#define XLOAD(c, r)                                  \
    {                                                \
        const float* xsrc_ = xp + (c) * 64;          \
        (r)[0] = *(const float4*)(xsrc_);            \
        (r)[1] = *(const float4*)(xsrc_ + 4);        \
        (r)[2] = *(const float4*)(xsrc_ + 32);       \
        (r)[3] = *(const float4*)(xsrc_ + 36);       \
    }

    WLOAD(0, 0);
    XLOAD(0, xr[0]);

    for (int c = 0; c < 8; c++) {
        int p = c & 1;
        __syncthreads();
        if (c < 7) {
            WLOAD(c + 1, p ^ 1);
            XLOAD(c + 1, xr[p ^ 1]);
        }
#pragma unroll
        for (int ki = 0; ki < 2; ki++) {
            float f[8];
            f[0] = xr[p][ki * 2].x; f[1] = xr[p][ki * 2].y; f[2] = xr[p][ki * 2].z; f[3] = xr[p][ki * 2].w;
            f[4] = xr[p][ki * 2 + 1].x; f[5] = xr[p][ki * 2 + 1].y; f[6] = xr[p][ki * 2 + 1].z; f[7] = xr[p][ki * 2 + 1].w;
            unsigned int u[8], lu[8];
#pragma unroll
            for (int j = 0; j < 8; j++) u[j] = __float_as_uint(f[j]);
            union { uint4 u4; bf16x8 v; } H, L;
            H.u4.x = __builtin_amdgcn_perm(u[1], u[0], 0x07060302u);
            H.u4.y = __builtin_amdgcn_perm(u[3], u[2], 0x07060302u);
            H.u4.z = __builtin_amdgcn_perm(u[5], u[4], 0x07060302u);
            H.u4.w = __builtin_amdgcn_perm(u[7], u[6], 0x07060302u);
#pragma unroll
            for (int j = 0; j < 8; j++)
                lu[j] = __float_as_uint(f[j] - __uint_as_float(u[j] & 0xFFFF0000u));
            L.u4.x = __builtin_amdgcn_perm(lu[1], lu[0], 0x07060302u);
            L.u4.y = __builtin_amdgcn_perm(lu[3], lu[2], 0x07060302u);
            L.u4.z = __builtin_amdgcn_perm(lu[5], lu[4], 0x07060302u);
            L.u4.w = __builtin_amdgcn_perm(lu[7], lu[6], 0x07060302u);
            int kq = ki * 4 + q;
#pragma unroll
            for (int ct = 0; ct < 4; ct++) {
                int slot = kq * 64 + ct * 16 + m;
                bf16x8 bh = *(const bf16x8*)&wlds[p][slot * 8];
                bf16x8 bl = *(const bf16x8*)&wlds[p][4096 + slot * 8];
                acc[ct] = __builtin_amdgcn_mfma_f32_16x16x32_bf16(H.v, bh, acc[ct], 0, 0, 0);
                acc[ct] = __builtin_amdgcn_mfma_f32_16x16x32_bf16(L.v, bh, acc[ct], 0, 0, 0);
                acc[ct] = __builtin_amdgcn_mfma_f32_16x16x32_bf16(H.v, bl, acc[ct], 0, 0, 0);
            }
        }
    }
    int rbase = gb * 64 + wave * 16 + q * 4;
#pragma unroll
    for (int r = 0; r < 4; r++) {
        int ro = rbase + r;
        if (ro < N) {
#pragma unroll
            for (int ct = 0; ct < 4; ct++)
                hb_out[(size_t)ro * C1 + ct * 16 + m] = f32_to_bf16_rne(acc[ct][r]);
        }
    }

    // ----- fused attn1: stash fp32 h into LDS, compute el/er for this block's 64 rows -----
    __syncthreads();   // all waves done reading wlds before reuse
    float* hst = (float*)&wlds[0][0];   // [64][69] floats = 17.6 KB
    {
        int rr = wave * 16 + q * 4;
#pragma unroll
        for (int r = 0; r < 4; r++)
#pragma unroll
            for (int ct = 0; ct < 4; ct++)
                hst[(rr + r) * 69 + ct * 16 + m] = acc[ct][r];
    }
    __syncthreads();
    for (int id = tid; id < 512; id += 256) {
        int r = id >> 3, hd = id & 7;
        int nn = gb * 64 + r;
        if (nn < N) {
            float e_l = 0.f, e_r = 0.f;
#pragma unroll
            for (int f = 0; f < 8; f++) {
                float v = hst[r * 69 + hd * 8 + f];
                e_l += v * al[hd * 8 + f];
                e_r += v * ar[hd * 8 + f];
            }
            el[(size_t)nn * NH + hd] = e_l;
            er[(size_t)nn * NH + hd] = e_r;
        }
    }
#undef WLOAD
#undef XLOAD
}

// ---------------- layer1: one wave per node, quarter-wave = edge slot, uint2 hb gathers, csr prefetch ----
// lane L: quarter q=L>>4 handles edges i+q; f=L&15 owns features 4f..4f+3 (head f>>1).
__global__ __launch_bounds__(256) void l1_wave_k(const unsigned short* __restrict__ hb,
                                                 const float* __restrict__ el, const float* __restrict__ er,
                                                 const int* __restrict__ rowp, const int* __restrict__ deg,
                                                 const int* __restrict__ csr_src, const float* __restrict__ b1,
                                                 float* __restrict__ h1out, int N) {
    int n = (blockIdx.x * 256 + threadIdx.x) >> 6;   // node = global wave id
    if (n >= N) return;
    int lane = threadIdx.x & 63;
    int q = lane >> 4;
    int f = lane & 15;
    int hd = f >> 1;
    int start = rowp[n], cnt = deg[n];
    float erd = er[(size_t)n * NH + hd];
    const uint2* hb64 = (const uint2*)hb;   // row = 16 uint2 (64 bf16)
    const int* cp = csr_src + start;
    float a0 = 0.f, a1 = 0.f, a2 = 0.f, a3 = 0.f, s = 0.f;
    if (cnt > 0) {
        int lastc = cnt - 1;
        int c0 = cp[(q < cnt) ? q : lastc];
        int c1 = cp[(4 + q < cnt) ? 4 + q : lastc];
        int i = 0;
        while (i + 8 < cnt) {
            int i8 = i + 8;
            int c2 = cp[(i8 + q < cnt) ? i8 + q : lastc];
            int c3 = cp[(i8 + 4 + q < cnt) ? i8 + 4 + q : lastc];
            float e0 = el[(size_t)c0 * NH + hd] + erd;
            float e1 = el[(size_t)c1 * NH + hd] + erd;
            uint2 v0 = hb64[(size_t)c0 * 16 + f];
            uint2 v1 = hb64[(size_t)c1 * 16 + f];
            e0 = e0 > 0.f ? e0 : NEG * e0;
            e1 = e1 > 0.f ? e1 : NEG * e1;
            float w0 = __expf(e0), w1 = __expf(e1);
            s += w0 + w1;
            a0 += w0 * __uint_as_float(v0.x << 16) + w1 * __uint_as_float(v1.x << 16);
            a1 += w0 * __uint_as_float(v0.x & 0xFFFF0000u) + w1 * __uint_as_float(v1.x & 0xFFFF0000u);
            a2 += w0 * __uint_as_float(v0.y << 16) + w1 * __uint_as_float(v1.y << 16);
            a3 += w0 * __uint_as_float(v0.y & 0xFFFF0000u) + w1 * __uint_as_float(v1.y & 0xFFFF0000u);
            c0 = c2; c1 = c3; i = i8;
        }
        {   // masked tail: edges i+q and i+4+q
            bool m0 = (i + q) < cnt, m1 = (i + 4 + q) < cnt;
            float e0 = el[(size_t)c0 * NH + hd] + erd;
            float e1 = el[(size_t)c1 * NH + hd] + erd;
            uint2 v0 = hb64[(size_t)c0 * 16 + f];
            uint2 v1 = hb64[(size_t)c1 * 16 + f];
            e0 = e0 > 0.f ? e0 : NEG * e0;
            e1 = e1 > 0.f ? e1 : NEG * e1;
            float w0 = m0 ? __expf(e0) : 0.f;
            float w1 = m1 ? __expf(e1) : 0.f;
            s += w0 + w1;
            a0 += w0 * __uint_as_float(v0.x << 16) + w1 * __uint_as_float(v1.x << 16);
            a1 += w0 * __uint_as_float(v0.x & 0xFFFF0000u) + w1 * __uint_as_float(v1.x & 0xFFFF0000u);
            a2 += w0 * __uint_as_float(v0.y << 16) + w1 * __uint_as_float(v1.y << 16);
            a3 += w0 * __uint_as_float(v0.y & 0xFFFF0000u) + w1 * __uint_as_float(v1.y & 0xFFFF0000u);
        }
    }
    // cross-quarter reduce
    a0 += __shfl_xor(a0, 16); a0 += __shfl_xor(a0, 32);
    a1 += __shfl_xor(a1, 16); a1 += __shfl_xor(a1, 32);
    a2 += __shfl_xor(a2, 16); a2 += __shfl_xor(a2, 32);
    a3 += __shfl_xor(a3, 16); a3 += __shfl_xor(a3, 32);
    s  += __shfl_xor(s, 16);  s  += __shfl_xor(s, 32);
    float sinv = (s > 0.f) ? 1.f / s : 0.f;
    float4 bv = *(const float4*)(b1 + f * 4);
    float o0 = a0 * sinv + bv.x;
    float o1 = a1 * sinv + bv.y;
    float o2 = a2 * sinv + bv.z;
    float o3 = a3 * sinv + bv.w;
    o0 = o0 > 0.f ? o0 : (__expf(o0) - 1.f);
    o1 = o1 > 0.f ? o1 : (__expf(o1) - 1.f);
    o2 = o2 > 0.f ? o2 : (__expf(o2) - 1.f);
    o3 = o3 > 0.f ? o3 : (__expf(o3) - 1.f);
    if (q == 0) *(float4*)(h1out + (size_t)n * C1 + f * 4) = make_float4(o0, o1, o2, o3);
}

// ---------------- GEMM2 via split-bf16 MFMA + attn2: h2b[N,40] bf16, el2/er2 fp32 ----------------
__global__ __launch_bounds__(256) void gemm2_attn2_k(const float* __restrict__ h1,
                                                     const unsigned short* __restrict__ w2t_hi,
                                                     const unsigned short* __restrict__ w2t_lo,
                                                     const float* __restrict__ al2, const float* __restrict__ ar2,
                                                     unsigned short* __restrict__ h2b, float* __restrict__ el2,
                                                     float* __restrict__ er2, int N) {
    __shared__ float h2s[64][49];   // 12.5 KB, stride 49 kills bank conflicts on attn2 reads
    __shared__ float a2s[2 * C2];
    int t = threadIdx.x;
    int wave = t >> 6, lane = t & 63;
    int m = lane & 15, q = lane >> 4;
    int n0 = blockIdx.x * 64;
    if (t < C2) a2s[t] = al2[t];
    else if (t < 2 * C2) a2s[t] = ar2[t - C2];
    int row = n0 + wave * 16 + m;
    int row_c = row < N ? row : N - 1;
    const float* hp = h1 + (size_t)row_c * C1 + q * 8;
    f32x4 acc[3];
#pragma unroll
    for (int ct = 0; ct < 3; ct++) acc[ct] = (f32x4){0.f, 0.f, 0.f, 0.f};
#pragma unroll
    for (int ks = 0; ks < 2; ks++) {
        float4 r0 = *(const float4*)(hp + ks * 32);
        float4 r1 = *(const float4*)(hp + ks * 32 + 4);
        float f[8];
        f[0] = r0.x; f[1] = r0.y; f[2] = r0.z; f[3] = r0.w;
        f[4] = r1.x; f[5] = r1.y; f[6] = r1.z; f[7] = r1.w;
        unsigned int u[8], lu[8];
#pragma unroll
        for (int j = 0; j < 8; j++) u[j] = __float_as_uint(f[j]);
        union { uint4 u4; bf16x8 v; } H, L;
        H.u4.x = __builtin_amdgcn_perm(u[1], u[0], 0x07060302u);
        H.u4.y = __builtin_amdgcn_perm(u[3], u[2], 0x07060302u);
        H.u4.z = __builtin_amdgcn_perm(u[5], u[4], 0x07060302u);
        H.u4.w = __builtin_amdgcn_perm(u[7], u[6], 0x07060302u);
#pragma unroll
        for (int j = 0; j < 8; j++)
            lu[j] = __float_as_uint(f[j] - __uint_as_float(u[j] & 0xFFFF0000u));
        L.u4.x = __builtin_amdgcn_perm(lu[1], lu[0], 0x07060302u);
        L.u4.y = __builtin_amdgcn_perm(lu[3], lu[2], 0x07060302u);
        L.u4.z = __builtin_amdgcn_perm(lu[5], lu[4], 0x07060302u);
        L.u4.w = __builtin_amdgcn_perm(lu[7], lu[6], 0x07060302u);
        int kb = ks * 32 + q * 8;
#pragma unroll
        for (int ct = 0; ct < 3; ct++) {
            int col = ct * 16 + m;
            bf16x8 bh = *(const bf16x8*)(w2t_hi + col * 64 + kb);
            bf16x8 bl = *(const bf16x8*)(w2t_lo + col * 64 + kb);
            acc[ct] = __builtin_amdgcn_mfma_f32_16x16x32_bf16(H.v, bh, acc[ct], 0, 0, 0);
            acc[ct] = __builtin_amdgcn_mfma_f32_16x16x32_bf16(L.v, bh, acc[ct], 0, 0, 0);
            acc[ct] = __builtin_amdgcn_mfma_f32_16x16x32_bf16(H.v, bl, acc[ct], 0, 0, 0);
        }
    }
    int rl = wave * 16 + q * 4;
#pragma unroll
    for (int ct = 0; ct < 3; ct++)
#pragma unroll
        for (int r = 0; r < 4; r++) h2s[rl + r][ct * 16 + m] = acc[ct][r];
    __syncthreads();
    // write unpadded bf16 rows: 20 dwords per row
    unsigned int* h2d = (unsigned int*)h2b;
    for (int o = t; o < 64 * 20; o += 256) {
        int r = o / 20, cd = o % 20;
        int nn = n0 + r;
        if (nn < N) {
            unsigned int lo16 = f32_to_bf16_rne(h2s[r][cd * 2]);
            unsigned int hi16 = f32_to_bf16_rne(h2s[r][cd * 2 + 1]);
            h2d[(size_t)nn * 20 + cd] = lo16 | (hi16 << 16);
        }
    }
    if (t < 64) {
        int nn = n0 + t;
        if (nn < N) {
            float e_l = 0.f, e_r = 0.f;
#pragma unroll
            for (int c = 0; c < C2; c++) {
                float v = h2s[t][c];
                e_l += v * a2s[c];
                e_r += v * a2s[C2 + c];
            }
            el2[nn] = e_l;
            er2[nn] = e_r;
        }
    }
}

// ---------------- layer2: 8 lanes/node; lanes sub<5 gather (80 B/row), csr prefetch ----------------
__global__ __launch_bounds__(256) void l2_fused_k(const unsigned short* __restrict__ h2b,
                                                  const float* __restrict__ el, const float* __restrict__ er,
                                                  const int* __restrict__ rowp, const int* __restrict__ deg,
                                                  const int* __restrict__ csr_src, const float* __restrict__ b2,
                                                  float* __restrict__ out, int N) {
    int tid = threadIdx.x;
    int n = blockIdx.x * 32 + (tid >> 3);
    int sub = tid & 7;
    if (n >= N) return;
    float vals[8];
    if (sub < 5) {
        int start = rowp[n], cnt = deg[n];
        float erd = er[n];
        float s = 0.f;
        float acc[8];
#pragma unroll
        for (int j = 0; j < 8; j++) acc[j] = 0.f;
        const int* cp = csr_src + start;
        if (cnt > 0) {
            int last = cnt - 1;
            int c0 = cp[0];
            int c1 = cp[1 < cnt ? 1 : last];
            int c2 = cp[2 < cnt ? 2 : last];
            int c3 = cp[3 < cnt ? 3 : last];
            int i = 0;
            while (i + 4 < cnt) {
                int i4 = i + 4;
                int p0 = cp[i4];
                int p1 = cp[(i4 + 1 < cnt) ? i4 + 1 : last];
                int p2 = cp[(i4 + 2 < cnt) ? i4 + 2 : last];
                int p3 = cp[(i4 + 3 < cnt) ? i4 + 3 : last];
                float e0 = el[c0], e1 = el[c1], e2 = el[c2], e3 = el[c3];
                bf16x8 v0 = *(const bf16x8*)(h2b + (size_t)c0 * C2 + sub * 8);
                bf16x8 v1 = *(const bf16x8*)(h2b + (size_t)c1 * C2 + sub * 8);
                bf16x8 v2 = *(const bf16x8*)(h2b + (size_t)c2 * C2 + sub * 8);
                bf16x8 v3 = *(const bf16x8*)(h2b + (size_t)c3 * C2 + sub * 8);
                e0 += erd; e1 += erd; e2 += erd; e3 += erd;
                e0 = e0 > 0.f ? e0 : NEG * e0;
                e1 = e1 > 0.f ? e1 : NEG * e1;
                e2 = e2 > 0.f ? e2 : NEG * e2;
                e3 = e3 > 0.f ? e3 : NEG * e3;
                float w0 = __expf(e0), w1 = __expf(e1), w2 = __expf(e2), w3 = __expf(e3);
                s += (w0 + w1) + (w2 + w3);
#pragma unroll
                for (int j = 0; j < 8; j++) {
                    acc[j] += w0 * bf16_to_f32((unsigned short)v0[j]) + w1 * bf16_to_f32((unsigned short)v1[j]) +
                              w2 * bf16_to_f32((unsigned short)v2[j]) + w3 * bf16_to_f32((unsigned short)v3[j]);
                }
                c0 = p0; c1 = p1; c2 = p2; c3 = p3; i = i4;
            }
            {   // masked tail
                bool m0 = i < cnt, m1 = i + 1 < cnt, m2 = i + 2 < cnt, m3 = i + 3 < cnt;
                float e0 = el[c0], e1 = el[c1], e2 = el[c2], e3 = el[c3];
                bf16x8 v0 = *(const bf16x8*)(h2b + (size_t)c0 * C2 + sub * 8);
                bf16x8 v1 = *(const bf16x8*)(h2b + (size_t)c1 * C2 + sub * 8);
                bf16x8 v2 = *(const bf16x8*)(h2b + (size_t)c2 * C2 + sub * 8);
                bf16x8 v3 = *(const bf16x8*)(h2b + (size_t)c3 * C2 + sub * 8);
                e0 += erd; e1 += erd; e2 += erd; e3 += erd;
                e0 = e0 > 0.f ? e0 : NEG * e0;
                e1 = e1 > 0.f ? e1 : NEG * e1;
                e2 = e2 > 0.f ? e2 : NEG * e2;
                e3 = e3 > 0.f ? e3 : NEG * e3;
                float w0 = m0 ? __expf(e0) : 0.f;
                float w1 = m1 ? __expf(e1) : 0.f;
                float w2 = m2 ? __expf(e2) : 0.f;
                float w3 = m3 ? __expf(e3) : 0.f;
                s += (w0 + w1) + (w2 + w3);
#pragma unroll
                for (int j = 0; j < 8; j++) {
                    acc[j] += w0 * bf16_to_f32((unsigned short)v0[j]) + w1 * bf16_to_f32((unsigned short)v1[j]) +
                              w2 * bf16_to_f32((unsigned short)v2[j]) + w3 * bf16_to_f32((unsigned short)v3[j]);
                }
            }
        }
        float sinv = (s > 0.f) ? 1.f / s : 0.f;
        const float* bp = b2 + sub * 8;
#pragma unroll
        for (int j = 0; j < 8; j++) vals[j] = acc[j] * sinv + bp[j];
    } else {
#pragma unroll
        for (int j = 0; j < 8; j++) vals[j] = -1e30f;
    }
    float mx = vals[0];
#pragma unroll
    for (int j = 1; j < 8; j++) mx = fmaxf(mx, vals[j]);
#pragma unroll
    for (int off = 1; off < 8; off <<= 1) mx = fmaxf(mx, __shfl_xor(mx, off, 8));
    float se = 0.f;
#pragma unroll
    for (int j = 0; j < 8; j++) se += __expf(vals[j] - mx);
#pragma unroll
    for (int off = 1; off < 8; off <<= 1) se += __shfl_xor(se, off, 8);
    float ls = __logf(se) + mx;
    if (sub < 5) {
        float* op = out + (size_t)n * C2 + sub * 8;
        *(float4*)(op) = make_float4(vals[0] - ls, vals[1] - ls, vals[2] - ls, vals[3] - ls);
        *(float4*)(op + 4) = make_float4(vals[4] - ls, vals[5] - ls, vals[6] - ls, vals[7] - ls);
    }
}

extern "C" void kernel_launch(void* const* d_in, const int* in_sizes, int n_in,
                              void* d_out, int out_size, void* d_ws, size_t ws_size,
                              hipStream_t stream) {
    (void)n_in; (void)out_size; (void)ws_size;
    const float* x   = (const float*)d_in[0];
    const int*   src = (const int*)d_in[1];
    const int*   dst = (const int*)d_in[2];
    const float* W1  = (const float*)d_in[3];
    const float* al1 = (const float*)d_in[4];
    const float* ar1 = (const float*)d_in[5];
    const float* b1  = (const float*)d_in[6];
    const float* W2  = (const float*)d_in[7];
    const float* al2 = (const float*)d_in[8];
    const float* ar2 = (const float*)d_in[9];
    const float* b2  = (const float*)d_in[10];
    float* out = (float*)d_out;
    const int N = in_sizes[0] / IN_F;
    const int E = in_sizes[1];

    char* w = (char*)d_ws;
    auto alloc = [&](size_t bytes) -> char* {
        char* p = w;
        w += (bytes + 255) & ~(size_t)255;
        return p;
    };
    int* deg     = (int*)alloc((size_t)N * 4);
    int* rowp    = (int*)alloc((size_t)N * 4);
    int* bsums   = (int*)alloc(512);
    int* pos     = (int*)alloc((size_t)E * 4);
    int* csr_src = (int*)alloc((size_t)E * 4);
    unsigned short* wt_hi = (unsigned short*)alloc((size_t)IN_F * C1 * 2);
    unsigned short* wt_lo = (unsigned short*)alloc((size_t)IN_F * C1 * 2);
    unsigned short* w2t_hi = (unsigned short*)alloc((size_t)48 * 64 * 2);
    unsigned short* w2t_lo = (unsigned short*)alloc((size_t)48 * 64 * 2);
    unsigned short* hb    = (unsigned short*)alloc((size_t)N * C1 * 2);
    float* el1   = (float*)alloc((size_t)N * NH * 4);
    float* er1   = (float*)alloc((size_t)N * NH * 4);
    float* h1    = (float*)alloc((size_t)N * C1 * 4);
    unsigned short* h2b = (unsigned short*)alloc((size_t)N * C2 * 2);
    float* el2   = (float*)alloc((size_t)N * 4);
    float* er2   = (float*)alloc((size_t)N * 4);

    hipMemsetAsync(deg, 0, (size_t)N * 4, stream);

    int HB = (E + 1023) / 1024;                        // hist / scatter blocks (4 edges/thread)
    int PREB = (IN_F * C1 + 48 * 64 + 255) / 256;      // preconvert blocks
    int GB = (N + 63) / 64;                            // gemm1 blocks
    int nb = (N + 1023) / 1024;

    hist_pre_k<<<HB + PREB, 256, 0, stream>>>(dst, deg, pos, E, HB, W1, W2, wt_hi, wt_lo, w2t_hi, w2t_lo);
    scan_local_k<<<nb, 1024, 0, stream>>>(deg, rowp, bsums, N);
    scan_add_k<<<nb, 1024, 0, stream>>>(rowp, bsums, N, nb);
    scat_gemm1_k<<<HB + GB, 256, 0, stream>>>(src, dst, rowp, pos, csr_src, E, HB,
                                              x, wt_hi, wt_lo, al1, ar1, hb, el1, er1, N);
    l1_wave_k<<<(N * 64 + 255) / 256, 256, 0, stream>>>(hb, el1, er1, rowp, deg, csr_src, b1, h1, N);
    gemm2_attn2_k<<<GB, 256, 0, stream>>>(h1, w2t_hi, w2t_lo, al2, ar2, h2b, el2, er2, N);
    l2_fused_k<<<(N + 31) / 32, 256, 0, stream>>>(h2b, el2, er2, rowp, deg, csr_src, b2, out, N);
}